// Round 1
// baseline (1519.678 us; speedup 1.0000x reference)
//
#include <hip/hip_runtime.h>

#define N_NODES 32768
#define N_EDGES 524288

// ---------------------------------------------------------------- utility
__global__ void k_zero_ints(int* __restrict__ p, int n) {
    int i = blockIdx.x * 256 + threadIdx.x;
    if (i < n) p[i] = 0;
}

__global__ void k_count_deg(const int* __restrict__ src, const int* __restrict__ dst,
                            int* __restrict__ out_deg, int* __restrict__ in_deg) {
    int e = blockIdx.x * 256 + threadIdx.x;
    if (e < N_EDGES) {
        atomicAdd(&out_deg[src[e]], 1);
        atomicAdd(&in_deg[dst[e]], 1);
    }
}

__global__ void k_norms(const int* __restrict__ out_deg, const int* __restrict__ in_deg,
                        float* __restrict__ ns, float* __restrict__ nd) {
    int i = blockIdx.x * 256 + threadIdx.x;
    if (i < N_NODES) {
        int od = out_deg[i], id = in_deg[i];
        ns[i] = od > 0 ? rsqrtf((float)od) : 1.0f;
        nd[i] = id > 0 ? rsqrtf((float)id) : 1.0f;
    }
}

// exclusive scan of in_deg (32768 values) -> row_ptr[0..32768], copy to cursor
__global__ void k_scan(const int* __restrict__ in_deg, int* __restrict__ row_ptr,
                       int* __restrict__ cursor) {
    __shared__ int part[1024];
    int t = threadIdx.x;
    int base = t * 32;
    int local[32];
    int s = 0;
    for (int i = 0; i < 32; i++) { local[i] = s; s += in_deg[base + i]; }
    part[t] = s;
    __syncthreads();
    for (int off = 1; off < 1024; off <<= 1) {
        int v = (t >= off) ? part[t - off] : 0;
        __syncthreads();
        part[t] += v;
        __syncthreads();
    }
    int prev = (t == 0) ? 0 : part[t - 1];
    for (int i = 0; i < 32; i++) {
        int v = prev + local[i];
        row_ptr[base + i] = v;
        cursor[base + i] = v;
    }
    if (t == 1023) row_ptr[N_NODES] = part[1023];
}

__global__ void k_build_csr(const int* __restrict__ src, const int* __restrict__ dst,
                            int* __restrict__ cursor, int* __restrict__ csr_src) {
    int e = blockIdx.x * 256 + threadIdx.x;
    if (e < N_EDGES) {
        int p = atomicAdd(&cursor[dst[e]], 1);
        csr_src[p] = src[e];
    }
}

// ------------------------------------------------ aggregation (gather, CSR by dst)
// one wave per dst node; lane owns 4 features (float4). agg[n] = nd[n]*sum h[s]*ns[s]
__global__ __launch_bounds__(256) void k_aggregate(
        const float* __restrict__ h, const float* __restrict__ ns,
        const int* __restrict__ row_ptr, const int* __restrict__ csr_src,
        const float* __restrict__ nd, float* __restrict__ agg) {
    int wave = threadIdx.x >> 6, lane = threadIdx.x & 63;
    int n = blockIdx.x * 4 + wave;
    int beg = row_ptr[n], end = row_ptr[n + 1];
    float4 acc = make_float4(0.f, 0.f, 0.f, 0.f);
    for (int e = beg; e < end; e++) {
        int s = csr_src[e];
        float sc = ns[s];
        float4 v = *(const float4*)(h + (size_t)s * 256 + lane * 4);
        acc.x += v.x * sc; acc.y += v.y * sc; acc.z += v.z * sc; acc.w += v.w * sc;
    }
    float sc = nd[n];
    acc.x *= sc; acc.y *= sc; acc.z *= sc; acc.w *= sc;
    *(float4*)(agg + (size_t)n * 256 + lane * 4) = acc;
}

// ------------------------------------------------ fp32 tiled GEMM  C = A@B + bias (opt leaky)
// threads = (BM/TM)*(BN/TN) = 256
template <int BM, int BN, int BK, int TM, int TN, bool LEAKY>
__global__ __launch_bounds__(256) void gemm_bias_act(
        const float* __restrict__ A, const float* __restrict__ B,
        const float* __restrict__ bias, float* __restrict__ C,
        int M, int N, int K) {
    __shared__ float As[BK][BM + 1];
    __shared__ float Bs[BK][BN + 1];
    const int tid = threadIdx.x;
    const int tcols = BN / TN;
    const int tr = tid / tcols;
    const int tc = tid % tcols;
    const int rowBase = blockIdx.y * BM;
    const int colBase = blockIdx.x * BN;
    float acc[TM][TN];
#pragma unroll
    for (int i = 0; i < TM; i++)
#pragma unroll
        for (int j = 0; j < TN; j++) acc[i][j] = 0.f;

    for (int k0 = 0; k0 < K; k0 += BK) {
        for (int i = tid; i < BM * BK; i += 256) {
            int r = i / BK, c = i % BK;
            As[c][r] = A[(size_t)(rowBase + r) * K + k0 + c];
        }
        for (int i = tid; i < BK * BN; i += 256) {
            int r = i / BN, c = i % BN;
            Bs[r][c] = B[(size_t)(k0 + r) * N + colBase + c];
        }
        __syncthreads();
#pragma unroll
        for (int kk = 0; kk < BK; kk++) {
            float a[TM], b[TN];
#pragma unroll
            for (int i = 0; i < TM; i++) a[i] = As[kk][tr * TM + i];
#pragma unroll
            for (int j = 0; j < TN; j++) b[j] = Bs[kk][tc * TN + j];
#pragma unroll
            for (int i = 0; i < TM; i++)
#pragma unroll
                for (int j = 0; j < TN; j++) acc[i][j] += a[i] * b[j];
        }
        __syncthreads();
    }
#pragma unroll
    for (int i = 0; i < TM; i++) {
        int r = rowBase + tr * TM + i;
#pragma unroll
        for (int j = 0; j < TN; j++) {
            int c = colBase + tc * TN + j;
            float v = acc[i][j] + bias[c];
            if (LEAKY) v = v >= 0.f ? v : 0.01f * v;
            C[(size_t)r * N + c] = v;
        }
    }
}

// ------------------------------------------------ layernorm, one block (256 thr) per row
template <int WIDTH>
__global__ __launch_bounds__(256) void k_layernorm(float* __restrict__ h) {
    constexpr int PER = WIDTH / 256;
    float* p = h + (size_t)blockIdx.x * WIDTH;
    float v[PER];
    float s = 0.f, s2 = 0.f;
#pragma unroll
    for (int j = 0; j < PER; j++) {
        v[j] = p[threadIdx.x + 256 * j];
        s += v[j];
        s2 += v[j] * v[j];
    }
#pragma unroll
    for (int off = 32; off > 0; off >>= 1) {
        s += __shfl_down(s, off);
        s2 += __shfl_down(s2, off);
    }
    __shared__ float ss[4], ss2[4];
    int wave = threadIdx.x >> 6;
    if ((threadIdx.x & 63) == 0) { ss[wave] = s; ss2[wave] = s2; }
    __syncthreads();
    if (threadIdx.x == 0) {
        float t = 0.f, t2 = 0.f;
        for (int w = 0; w < 4; w++) { t += ss[w]; t2 += ss2[w]; }
        float mu = t / WIDTH;
        float var = t2 / WIDTH - mu * mu;
        ss[0] = mu;
        ss2[0] = rsqrtf(var + 1e-5f);
    }
    __syncthreads();
    float mu = ss[0], inv = ss2[0];
#pragma unroll
    for (int j = 0; j < PER; j++) p[threadIdx.x + 256 * j] = (v[j] - mu) * inv;
}

// ------------------------------------------------ mean-pool 256 nodes -> 1 row of 1024
__global__ __launch_bounds__(256) void k_pool(const float* __restrict__ h4,
                                              float* __restrict__ pooled) {
    int b = blockIdx.x, t = threadIdx.x;
    const float* base = h4 + (size_t)b * 256 * 1024 + t * 4;
    float4 acc = make_float4(0.f, 0.f, 0.f, 0.f);
    for (int n = 0; n < 256; n++) {
        float4 v = *(const float4*)(base + (size_t)n * 1024);
        acc.x += v.x; acc.y += v.y; acc.z += v.z; acc.w += v.w;
    }
    const float inv = 1.0f / 256.0f;
    acc.x *= inv; acc.y *= inv; acc.z *= inv; acc.w *= inv;
    *(float4*)(pooled + (size_t)b * 1024 + t * 4) = acc;
}

// ---------------------------------------------------------------- launch
extern "C" void kernel_launch(void* const* d_in, const int* in_sizes, int n_in,
                              void* d_out, int out_size, void* d_ws, size_t ws_size,
                              hipStream_t stream) {
    const float* x  = (const float*)d_in[0];
    const int*   src = (const int*)d_in[1];
    const int*   dst = (const int*)d_in[2];
    const float* W1 = (const float*)d_in[3];  const float* b1 = (const float*)d_in[4];
    const float* W2 = (const float*)d_in[5];  const float* b2 = (const float*)d_in[6];
    const float* W3 = (const float*)d_in[7];  const float* b3 = (const float*)d_in[8];
    const float* W4 = (const float*)d_in[9];  const float* b4 = (const float*)d_in[10];
    const float* Wm = (const float*)d_in[11]; const float* bm = (const float*)d_in[12];
    const float* Wsd = (const float*)d_in[13]; const float* bsd = (const float*)d_in[14];
    float* out = (float*)d_out;

    char* w = (char*)d_ws;
    float* agg    = (float*)w; w += (size_t)N_NODES * 256 * 4;
    float* h      = (float*)w; w += (size_t)N_NODES * 256 * 4;
    float* h4     = (float*)w; w += (size_t)N_NODES * 1024 * 4;
    float* pooled = (float*)w; w += (size_t)128 * 1024 * 4;
    float* ns     = (float*)w; w += (size_t)N_NODES * 4;
    float* nd     = (float*)w; w += (size_t)N_NODES * 4;
    int* out_deg  = (int*)w;   w += (size_t)N_NODES * 4;
    int* in_deg   = (int*)w;   w += (size_t)N_NODES * 4;   // contiguous after out_deg
    int* row_ptr  = (int*)w;   w += (size_t)(N_NODES + 1) * 4;
    int* cursor   = (int*)w;   w += (size_t)N_NODES * 4;
    int* csr_src  = (int*)w;   w += (size_t)N_EDGES * 4;

    // graph preprocessing (identical every call; inputs re-poisoned by harness)
    k_zero_ints<<<(2 * N_NODES + 255) / 256, 256, 0, stream>>>(out_deg, 2 * N_NODES);
    k_count_deg<<<N_EDGES / 256, 256, 0, stream>>>(src, dst, out_deg, in_deg);
    k_norms<<<N_NODES / 256, 256, 0, stream>>>(out_deg, in_deg, ns, nd);
    k_scan<<<1, 1024, 0, stream>>>(in_deg, row_ptr, cursor);
    k_build_csr<<<N_EDGES / 256, 256, 0, stream>>>(src, dst, cursor, csr_src);

    // layer 1 (input = x)
    k_aggregate<<<N_NODES / 4, 256, 0, stream>>>(x, ns, row_ptr, csr_src, nd, agg);
    gemm_bias_act<64, 64, 16, 4, 4, true>
        <<<dim3(256 / 64, N_NODES / 64), 256, 0, stream>>>(agg, W1, b1, h, N_NODES, 256, 256);
    k_layernorm<256><<<N_NODES, 256, 0, stream>>>(h);

    // layer 2
    k_aggregate<<<N_NODES / 4, 256, 0, stream>>>(h, ns, row_ptr, csr_src, nd, agg);
    gemm_bias_act<64, 64, 16, 4, 4, true>
        <<<dim3(4, N_NODES / 64), 256, 0, stream>>>(agg, W2, b2, h, N_NODES, 256, 256);
    k_layernorm<256><<<N_NODES, 256, 0, stream>>>(h);

    // layer 3
    k_aggregate<<<N_NODES / 4, 256, 0, stream>>>(h, ns, row_ptr, csr_src, nd, agg);
    gemm_bias_act<64, 64, 16, 4, 4, true>
        <<<dim3(4, N_NODES / 64), 256, 0, stream>>>(agg, W3, b3, h, N_NODES, 256, 256);
    k_layernorm<256><<<N_NODES, 256, 0, stream>>>(h);

    // layer 4 (256 -> 1024)
    k_aggregate<<<N_NODES / 4, 256, 0, stream>>>(h, ns, row_ptr, csr_src, nd, agg);
    gemm_bias_act<64, 64, 16, 4, 4, true>
        <<<dim3(1024 / 64, N_NODES / 64), 256, 0, stream>>>(agg, W4, b4, h4, N_NODES, 1024, 256);
    k_layernorm<1024><<<N_NODES, 256, 0, stream>>>(h4);

    // pool + LN + heads
    k_pool<<<128, 256, 0, stream>>>(h4, pooled);
    k_layernorm<1024><<<128, 256, 0, stream>>>(pooled);
    gemm_bias_act<32, 32, 16, 2, 2, false>
        <<<dim3(1024 / 32, 128 / 32), 256, 0, stream>>>(pooled, Wm, bm, out, 128, 1024, 1024);
    gemm_bias_act<32, 32, 16, 2, 2, false>
        <<<dim3(1024 / 32, 128 / 32), 256, 0, stream>>>(pooled, Wsd, bsd, out + 128 * 1024, 128, 1024, 1024);
}

// Round 2
// 761.607 us; speedup vs baseline: 1.9954x; 1.9954x over previous
//
#include <hip/hip_runtime.h>

#define N_NODES 32768
#define N_EDGES 524288

typedef __attribute__((ext_vector_type(8))) short short8;
typedef __attribute__((ext_vector_type(4))) float floatx4;

#define GLOBAL_AS __attribute__((address_space(1)))
#define LDS_AS __attribute__((address_space(3)))

__device__ __forceinline__ unsigned short f2bf(float x) {
    union { float f; unsigned u; } v; v.f = x;
    unsigned r = v.u + 0x7FFF + ((v.u >> 16) & 1);
    return (unsigned short)(r >> 16);
}

// ---------------------------------------------------------------- utility
__global__ void k_zero_ints(int* __restrict__ p, int n) {
    int i = blockIdx.x * 256 + threadIdx.x;
    if (i < n) p[i] = 0;
}

__global__ void k_count_deg(const int* __restrict__ src, const int* __restrict__ dst,
                            int* __restrict__ out_deg, int* __restrict__ in_deg) {
    int e = blockIdx.x * 256 + threadIdx.x;
    if (e < N_EDGES) {
        atomicAdd(&out_deg[src[e]], 1);
        atomicAdd(&in_deg[dst[e]], 1);
    }
}

__global__ void k_norms(const int* __restrict__ out_deg, const int* __restrict__ in_deg,
                        float* __restrict__ ns, float* __restrict__ nd) {
    int i = blockIdx.x * 256 + threadIdx.x;
    if (i < N_NODES) {
        int od = out_deg[i], id = in_deg[i];
        ns[i] = od > 0 ? rsqrtf((float)od) : 1.0f;
        nd[i] = id > 0 ? rsqrtf((float)id) : 1.0f;
    }
}

__global__ void k_scan(const int* __restrict__ in_deg, int* __restrict__ row_ptr,
                       int* __restrict__ cursor) {
    __shared__ int part[1024];
    int t = threadIdx.x;
    int base = t * 32;
    int local[32];
    int s = 0;
    for (int i = 0; i < 32; i++) { local[i] = s; s += in_deg[base + i]; }
    part[t] = s;
    __syncthreads();
    for (int off = 1; off < 1024; off <<= 1) {
        int v = (t >= off) ? part[t - off] : 0;
        __syncthreads();
        part[t] += v;
        __syncthreads();
    }
    int prev = (t == 0) ? 0 : part[t - 1];
    for (int i = 0; i < 32; i++) {
        int v = prev + local[i];
        row_ptr[base + i] = v;
        cursor[base + i] = v;
    }
    if (t == 1023) row_ptr[N_NODES] = part[1023];
}

__global__ void k_build_csr(const int* __restrict__ src, const int* __restrict__ dst,
                            int* __restrict__ cursor, int* __restrict__ csr_src) {
    int e = blockIdx.x * 256 + threadIdx.x;
    if (e < N_EDGES) {
        int p = atomicAdd(&cursor[dst[e]], 1);
        csr_src[p] = src[e];
    }
}

// ---------------------------------------------- weight transpose fp32[K][N] -> bf16[N][K]
__global__ __launch_bounds__(256) void k_transpose_bf16(const float* __restrict__ W,
                                                        unsigned short* __restrict__ Wt,
                                                        int K, int N) {
    __shared__ float t[32][33];
    int tx = threadIdx.x & 31, ty = threadIdx.x >> 5;  // ty 0..7
    int n0 = blockIdx.x * 32, k0 = blockIdx.y * 32;
    for (int r = 0; r < 32; r += 8)
        t[ty + r][tx] = W[(size_t)(k0 + ty + r) * N + n0 + tx];
    __syncthreads();
    for (int r = 0; r < 32; r += 8) {
        int n = ty + r;
        Wt[(size_t)(n0 + n) * K + k0 + tx] = f2bf(t[tx][n]);
    }
}

// ------------------------------------------------ aggregation (gather, CSR by dst)
// one wave per dst node; lane owns 4 features. writes bf16 (GEMM A operand)
__global__ __launch_bounds__(256) void k_aggregate(
        const float* __restrict__ h, const float* __restrict__ ns,
        const int* __restrict__ row_ptr, const int* __restrict__ csr_src,
        const float* __restrict__ nd, unsigned short* __restrict__ aggb) {
    int wave = threadIdx.x >> 6, lane = threadIdx.x & 63;
    int n = blockIdx.x * 4 + wave;
    int beg = row_ptr[n], end = row_ptr[n + 1];
    float4 acc = make_float4(0.f, 0.f, 0.f, 0.f);
    for (int e = beg; e < end; e++) {
        int s = csr_src[e];
        float sc = ns[s];
        float4 v = *(const float4*)(h + (size_t)s * 256 + lane * 4);
        acc.x += v.x * sc; acc.y += v.y * sc; acc.z += v.z * sc; acc.w += v.w * sc;
    }
    float sc = nd[n];
    ushort4 o;
    o.x = f2bf(acc.x * sc); o.y = f2bf(acc.y * sc);
    o.z = f2bf(acc.z * sc); o.w = f2bf(acc.w * sc);
    *(ushort4*)(aggb + (size_t)n * 256 + lane * 4) = o;
}

// ------------------------------------------------ bf16 MFMA GEMM (m97 structure)
// A: MxK bf16 row-major; Bt: NxK bf16 row-major (pre-transposed); C: MxN fp32
// 128x128 tile, BK=32, 256 thr = 4 waves in 2x2, each wave 64x64 = 4x4 MFMA tiles
template <bool LEAKY>
__global__ __launch_bounds__(256) void gemm_mfma(
        const unsigned short* __restrict__ A, const unsigned short* __restrict__ Bt,
        const float* __restrict__ bias, float* __restrict__ C,
        int M, int N, int K) {
    __shared__ __align__(16) unsigned short As[128 * 32];
    __shared__ __align__(16) unsigned short Bs[128 * 32];
    const int tid = threadIdx.x;
    const int lane = tid & 63;
    const int w = tid >> 6;
    const int wr = (w >> 1) * 64;
    const int wc = (w & 1) * 64;
    const int rowBase = blockIdx.y * 128;
    const int colBase = blockIdx.x * 128;

    floatx4 acc[4][4];
#pragma unroll
    for (int i = 0; i < 4; i++)
#pragma unroll
        for (int j = 0; j < 4; j++) acc[i][j] = (floatx4){0.f, 0.f, 0.f, 0.f};

    // staging: wave w fills tile rows [w*32, w*32+32) of both As and Bs.
    // per global_load_lds (16B/lane): lane L -> row r0 + (L>>2), k-chunk (L&3)*8.
    const int srow = w * 32 + (lane >> 2);
    const int kc = (lane & 3) * 8;
    const unsigned short* gA = A + (size_t)(rowBase + srow) * K + kc;
    const unsigned short* gB = Bt + (size_t)(colBase + srow) * K + kc;
    unsigned short* lA = As + (w * 32) * 32;  // wave-uniform; HW adds lane*16B
    unsigned short* lB = Bs + (w * 32) * 32;

    const int q = lane >> 4;
    const int ln = lane & 15;

    for (int k0 = 0; k0 < K; k0 += 32) {
        __syncthreads();
        __builtin_amdgcn_global_load_lds((const GLOBAL_AS short*)(gA + k0),
                                         (LDS_AS short*)lA, 16, 0, 0);
        __builtin_amdgcn_global_load_lds((const GLOBAL_AS short*)(gA + k0 + (size_t)16 * K),
                                         (LDS_AS short*)(lA + 16 * 32), 16, 0, 0);
        __builtin_amdgcn_global_load_lds((const GLOBAL_AS short*)(gB + k0),
                                         (LDS_AS short*)lB, 16, 0, 0);
        __builtin_amdgcn_global_load_lds((const GLOBAL_AS short*)(gB + k0 + (size_t)16 * K),
                                         (LDS_AS short*)(lB + 16 * 32), 16, 0, 0);
        __syncthreads();
        short8 af[4], bf[4];
#pragma unroll
        for (int i = 0; i < 4; i++)
            af[i] = *(const short8*)(As + (wr + i * 16 + ln) * 32 + q * 8);
#pragma unroll
        for (int j = 0; j < 4; j++)
            bf[j] = *(const short8*)(Bs + (wc + j * 16 + ln) * 32 + q * 8);
#pragma unroll
        for (int i = 0; i < 4; i++)
#pragma unroll
            for (int j = 0; j < 4; j++)
                acc[i][j] = __builtin_amdgcn_mfma_f32_16x16x32_bf16(af[i], bf[j], acc[i][j], 0, 0, 0);
    }
    // C/D layout: col = lane&15, row = (lane>>4)*4 + reg  [verified m89/m91]
#pragma unroll
    for (int i = 0; i < 4; i++) {
#pragma unroll
        for (int j = 0; j < 4; j++) {
#pragma unroll
            for (int r = 0; r < 4; r++) {
                int row = rowBase + wr + i * 16 + q * 4 + r;
                int col = colBase + wc + j * 16 + ln;
                float v = acc[i][j][r] + bias[col];
                if (LEAKY) v = v >= 0.f ? v : 0.01f * v;
                C[(size_t)row * N + col] = v;
            }
        }
    }
}

// ------------------------------------------------ layernorm, one block (256 thr) per row
// optionally emits a bf16 copy (hb != nullptr)
template <int WIDTH>
__global__ __launch_bounds__(256) void k_layernorm(float* __restrict__ h,
                                                   unsigned short* __restrict__ hb) {
    constexpr int PER = WIDTH / 256;
    float* p = h + (size_t)blockIdx.x * WIDTH;
    float v[PER];
    float s = 0.f, s2 = 0.f;
    if constexpr (PER == 4) {
        float4 t4 = *(const float4*)(p + threadIdx.x * 4);
        v[0] = t4.x; v[1] = t4.y; v[2] = t4.z; v[3] = t4.w;
    } else {
#pragma unroll
        for (int j = 0; j < PER; j++) v[j] = p[threadIdx.x * PER + j];
    }
#pragma unroll
    for (int j = 0; j < PER; j++) { s += v[j]; s2 += v[j] * v[j]; }
#pragma unroll
    for (int off = 32; off > 0; off >>= 1) {
        s += __shfl_down(s, off);
        s2 += __shfl_down(s2, off);
    }
    __shared__ float ss[4], ss2[4];
    int wave = threadIdx.x >> 6;
    if ((threadIdx.x & 63) == 0) { ss[wave] = s; ss2[wave] = s2; }
    __syncthreads();
    if (threadIdx.x == 0) {
        float t = 0.f, t2 = 0.f;
        for (int w = 0; w < 4; w++) { t += ss[w]; t2 += ss2[w]; }
        float mu = t / WIDTH;
        float var = t2 / WIDTH - mu * mu;
        ss[0] = mu;
        ss2[0] = rsqrtf(var + 1e-5f);
    }
    __syncthreads();
    float mu = ss[0], inv = ss2[0];
#pragma unroll
    for (int j = 0; j < PER; j++) v[j] = (v[j] - mu) * inv;
    if constexpr (PER == 4) {
        *(float4*)(p + threadIdx.x * 4) = make_float4(v[0], v[1], v[2], v[3]);
    } else {
#pragma unroll
        for (int j = 0; j < PER; j++) p[threadIdx.x * PER + j] = v[j];
    }
    if (hb) {
        unsigned short* pb = hb + (size_t)blockIdx.x * WIDTH;
#pragma unroll
        for (int j = 0; j < PER; j++) pb[threadIdx.x * PER + j] = f2bf(v[j]);
    }
}

// ------------------------------------------------ mean-pool 256 nodes -> 1 row of 1024
__global__ __launch_bounds__(256) void k_pool(const float* __restrict__ h4,
                                              float* __restrict__ pooled) {
    int b = blockIdx.x, t = threadIdx.x;
    const float* base = h4 + (size_t)b * 256 * 1024 + t * 4;
    float4 acc = make_float4(0.f, 0.f, 0.f, 0.f);
    for (int n = 0; n < 256; n++) {
        float4 v = *(const float4*)(base + (size_t)n * 1024);
        acc.x += v.x; acc.y += v.y; acc.z += v.z; acc.w += v.w;
    }
    const float inv = 1.0f / 256.0f;
    acc.x *= inv; acc.y *= inv; acc.z *= inv; acc.w *= inv;
    *(float4*)(pooled + (size_t)b * 1024 + t * 4) = acc;
}

// ---------------------------------------------------------------- launch
extern "C" void kernel_launch(void* const* d_in, const int* in_sizes, int n_in,
                              void* d_out, int out_size, void* d_ws, size_t ws_size,
                              hipStream_t stream) {
    const float* x  = (const float*)d_in[0];
    const int*   src = (const int*)d_in[1];
    const int*   dst = (const int*)d_in[2];
    const float* W1 = (const float*)d_in[3];  const float* b1 = (const float*)d_in[4];
    const float* W2 = (const float*)d_in[5];  const float* b2 = (const float*)d_in[6];
    const float* W3 = (const float*)d_in[7];  const float* b3 = (const float*)d_in[8];
    const float* W4 = (const float*)d_in[9];  const float* b4 = (const float*)d_in[10];
    const float* Wm = (const float*)d_in[11]; const float* bm = (const float*)d_in[12];
    const float* Wsd = (const float*)d_in[13]; const float* bsd = (const float*)d_in[14];
    float* out = (float*)d_out;

    char* w = (char*)d_ws;
    unsigned short* aggb = (unsigned short*)w; w += (size_t)N_NODES * 256 * 2;
    float* h      = (float*)w; w += (size_t)N_NODES * 256 * 4;
    float* h4     = (float*)w; w += (size_t)N_NODES * 1024 * 4;
    float* pooled = (float*)w; w += (size_t)128 * 1024 * 4;
    unsigned short* pooledb = (unsigned short*)w; w += (size_t)128 * 1024 * 2;
    unsigned short* W1t = (unsigned short*)w; w += (size_t)256 * 256 * 2;
    unsigned short* W2t = (unsigned short*)w; w += (size_t)256 * 256 * 2;
    unsigned short* W3t = (unsigned short*)w; w += (size_t)256 * 256 * 2;
    unsigned short* W4t = (unsigned short*)w; w += (size_t)256 * 1024 * 2;
    unsigned short* Wmt = (unsigned short*)w; w += (size_t)1024 * 1024 * 2;
    unsigned short* Wst = (unsigned short*)w; w += (size_t)1024 * 1024 * 2;
    float* ns     = (float*)w; w += (size_t)N_NODES * 4;
    float* nd     = (float*)w; w += (size_t)N_NODES * 4;
    int* out_deg  = (int*)w;   w += (size_t)N_NODES * 4;
    int* in_deg   = (int*)w;   w += (size_t)N_NODES * 4;
    int* row_ptr  = (int*)w;   w += (size_t)(N_NODES + 1) * 4;
    int* cursor   = (int*)w;   w += (size_t)N_NODES * 4;
    int* csr_src  = (int*)w;   w += (size_t)N_EDGES * 4;

    // weights -> bf16, transposed to [N][K]
    k_transpose_bf16<<<dim3(256 / 32, 256 / 32), 256, 0, stream>>>(W1, W1t, 256, 256);
    k_transpose_bf16<<<dim3(256 / 32, 256 / 32), 256, 0, stream>>>(W2, W2t, 256, 256);
    k_transpose_bf16<<<dim3(256 / 32, 256 / 32), 256, 0, stream>>>(W3, W3t, 256, 256);
    k_transpose_bf16<<<dim3(1024 / 32, 256 / 32), 256, 0, stream>>>(W4, W4t, 256, 1024);
    k_transpose_bf16<<<dim3(1024 / 32, 1024 / 32), 256, 0, stream>>>(Wm, Wmt, 1024, 1024);
    k_transpose_bf16<<<dim3(1024 / 32, 1024 / 32), 256, 0, stream>>>(Wsd, Wst, 1024, 1024);

    // graph preprocessing
    k_zero_ints<<<(2 * N_NODES + 255) / 256, 256, 0, stream>>>(out_deg, 2 * N_NODES);
    k_count_deg<<<N_EDGES / 256, 256, 0, stream>>>(src, dst, out_deg, in_deg);
    k_norms<<<N_NODES / 256, 256, 0, stream>>>(out_deg, in_deg, ns, nd);
    k_scan<<<1, 1024, 0, stream>>>(in_deg, row_ptr, cursor);
    k_build_csr<<<N_EDGES / 256, 256, 0, stream>>>(src, dst, cursor, csr_src);

    // layer 1
    k_aggregate<<<N_NODES / 4, 256, 0, stream>>>(x, ns, row_ptr, csr_src, nd, aggb);
    gemm_mfma<true><<<dim3(256 / 128, N_NODES / 128), 256, 0, stream>>>(aggb, W1t, b1, h, N_NODES, 256, 256);
    k_layernorm<256><<<N_NODES, 256, 0, stream>>>(h, nullptr);

    // layer 2
    k_aggregate<<<N_NODES / 4, 256, 0, stream>>>(h, ns, row_ptr, csr_src, nd, aggb);
    gemm_mfma<true><<<dim3(2, N_NODES / 128), 256, 0, stream>>>(aggb, W2t, b2, h, N_NODES, 256, 256);
    k_layernorm<256><<<N_NODES, 256, 0, stream>>>(h, nullptr);

    // layer 3
    k_aggregate<<<N_NODES / 4, 256, 0, stream>>>(h, ns, row_ptr, csr_src, nd, aggb);
    gemm_mfma<true><<<dim3(2, N_NODES / 128), 256, 0, stream>>>(aggb, W3t, b3, h, N_NODES, 256, 256);
    k_layernorm<256><<<N_NODES, 256, 0, stream>>>(h, nullptr);

    // layer 4 (256 -> 1024)
    k_aggregate<<<N_NODES / 4, 256, 0, stream>>>(h, ns, row_ptr, csr_src, nd, aggb);
    gemm_mfma<true><<<dim3(1024 / 128, N_NODES / 128), 256, 0, stream>>>(aggb, W4t, b4, h4, N_NODES, 1024, 256);
    k_layernorm<1024><<<N_NODES, 256, 0, stream>>>(h4, nullptr);

    // pool + LN + heads
    k_pool<<<128, 256, 0, stream>>>(h4, pooled);
    k_layernorm<1024><<<128, 256, 0, stream>>>(pooled, pooledb);
    gemm_mfma<false><<<dim3(1024 / 128, 1), 256, 0, stream>>>(pooledb, Wmt, bm, out, 128, 1024, 1024);
    gemm_mfma<false><<<dim3(1024 / 128, 1), 256, 0, stream>>>(pooledb, Wst, bsd, out + 128 * 1024, 128, 1024, 1024);
}

// Round 3
// 591.619 us; speedup vs baseline: 2.5687x; 1.2873x over previous
//
#include <hip/hip_runtime.h>

#define N_NODES 32768
#define N_EDGES 524288

typedef __attribute__((ext_vector_type(8))) short short8;
typedef __attribute__((ext_vector_type(4))) float floatx4;

#define GLOBAL_AS __attribute__((address_space(1)))
#define LDS_AS __attribute__((address_space(3)))

__device__ __forceinline__ unsigned short f2bf(float x) {
    union { float f; unsigned u; } v; v.f = x;
    unsigned r = v.u + 0x7FFF + ((v.u >> 16) & 1);
    return (unsigned short)(r >> 16);
}
__device__ __forceinline__ float bf2f(unsigned short u) {
    union { unsigned u; float f; } v; v.u = ((unsigned)u) << 16;
    return v.f;
}

// ---------------------------------------------------------------- utility
__global__ void k_zero_ints(int* __restrict__ p, int n) {
    int i = blockIdx.x * 256 + threadIdx.x;
    if (i < n) p[i] = 0;
}

__global__ void k_count_deg(const int* __restrict__ src, const int* __restrict__ dst,
                            int* __restrict__ out_deg, int* __restrict__ in_deg) {
    int e = blockIdx.x * 256 + threadIdx.x;
    if (e < N_EDGES) {
        atomicAdd(&out_deg[src[e]], 1);
        atomicAdd(&in_deg[dst[e]], 1);
    }
}

__global__ void k_norms(const int* __restrict__ out_deg, const int* __restrict__ in_deg,
                        float* __restrict__ ns, float* __restrict__ nd) {
    int i = blockIdx.x * 256 + threadIdx.x;
    if (i < N_NODES) {
        int od = out_deg[i], id = in_deg[i];
        ns[i] = od > 0 ? rsqrtf((float)od) : 1.0f;
        nd[i] = id > 0 ? rsqrtf((float)id) : 1.0f;
    }
}

__global__ void k_scan(const int* __restrict__ in_deg, int* __restrict__ row_ptr,
                       int* __restrict__ cursor) {
    __shared__ int part[1024];
    int t = threadIdx.x;
    int base = t * 32;
    int local[32];
    int s = 0;
    for (int i = 0; i < 32; i++) { local[i] = s; s += in_deg[base + i]; }
    part[t] = s;
    __syncthreads();
    for (int off = 1; off < 1024; off <<= 1) {
        int v = (t >= off) ? part[t - off] : 0;
        __syncthreads();
        part[t] += v;
        __syncthreads();
    }
    int prev = (t == 0) ? 0 : part[t - 1];
    for (int i = 0; i < 32; i++) {
        int v = prev + local[i];
        row_ptr[base + i] = v;
        cursor[base + i] = v;
    }
    if (t == 1023) row_ptr[N_NODES] = part[1023];
}

__global__ void k_build_csr(const int* __restrict__ src, const int* __restrict__ dst,
                            int* __restrict__ cursor, int* __restrict__ csr_src) {
    int e = blockIdx.x * 256 + threadIdx.x;
    if (e < N_EDGES) {
        int p = atomicAdd(&cursor[dst[e]], 1);
        csr_src[p] = src[e];
    }
}

// ---------------------------------------------- weight transpose fp32[K][N] -> bf16[N][K]
__global__ __launch_bounds__(256) void k_transpose_bf16(const float* __restrict__ W,
                                                        unsigned short* __restrict__ Wt,
                                                        int K, int N) {
    __shared__ float t[32][33];
    int tx = threadIdx.x & 31, ty = threadIdx.x >> 5;  // ty 0..7
    int n0 = blockIdx.x * 32, k0 = blockIdx.y * 32;
    for (int r = 0; r < 32; r += 8)
        t[ty + r][tx] = W[(size_t)(k0 + ty + r) * N + n0 + tx];
    __syncthreads();
    for (int r = 0; r < 32; r += 8) {
        int n = ty + r;
        Wt[(size_t)(n0 + n) * K + k0 + tx] = f2bf(t[tx][n]);
    }
}

// ---------------------------------------------- x * ns[node] -> bf16 table (layer-1 gather input)
__global__ __launch_bounds__(256) void k_scale_x(const float* __restrict__ x,
                                                 const float* __restrict__ ns,
                                                 unsigned short* __restrict__ xsb) {
    int i = blockIdx.x * 256 + threadIdx.x;  // float4 index
    float4 v = ((const float4*)x)[i];
    float sc = ns[i >> 6];  // 64 float4 per 256-wide row
    ushort4 o;
    o.x = f2bf(v.x * sc); o.y = f2bf(v.y * sc);
    o.z = f2bf(v.z * sc); o.w = f2bf(v.w * sc);
    ((ushort4*)xsb)[i] = o;
}

// ------------------------------------------------ aggregation (gather, CSR by dst)
// table hs is bf16, pre-scaled by ns[src]. one wave per dst node; lane owns 4 feats.
__global__ __launch_bounds__(256) void k_aggregate(
        const unsigned short* __restrict__ hs, const int* __restrict__ row_ptr,
        const int* __restrict__ csr_src, const float* __restrict__ nd,
        unsigned short* __restrict__ aggb) {
    int wave = threadIdx.x >> 6, lane = threadIdx.x & 63;
    int n = blockIdx.x * 4 + wave;
    int beg = row_ptr[n], end = row_ptr[n + 1];
    float4 acc = make_float4(0.f, 0.f, 0.f, 0.f);
    int e = beg;
    for (; e + 4 <= end; e += 4) {
        int s0 = csr_src[e], s1 = csr_src[e + 1], s2 = csr_src[e + 2], s3 = csr_src[e + 3];
        ushort4 v0 = *(const ushort4*)(hs + (size_t)s0 * 256 + lane * 4);
        ushort4 v1 = *(const ushort4*)(hs + (size_t)s1 * 256 + lane * 4);
        ushort4 v2 = *(const ushort4*)(hs + (size_t)s2 * 256 + lane * 4);
        ushort4 v3 = *(const ushort4*)(hs + (size_t)s3 * 256 + lane * 4);
        acc.x += bf2f(v0.x) + bf2f(v1.x) + bf2f(v2.x) + bf2f(v3.x);
        acc.y += bf2f(v0.y) + bf2f(v1.y) + bf2f(v2.y) + bf2f(v3.y);
        acc.z += bf2f(v0.z) + bf2f(v1.z) + bf2f(v2.z) + bf2f(v3.z);
        acc.w += bf2f(v0.w) + bf2f(v1.w) + bf2f(v2.w) + bf2f(v3.w);
    }
    for (; e < end; e++) {
        int s = csr_src[e];
        ushort4 v = *(const ushort4*)(hs + (size_t)s * 256 + lane * 4);
        acc.x += bf2f(v.x); acc.y += bf2f(v.y);
        acc.z += bf2f(v.z); acc.w += bf2f(v.w);
    }
    float sc = nd[n];
    ushort4 o;
    o.x = f2bf(acc.x * sc); o.y = f2bf(acc.y * sc);
    o.z = f2bf(acc.z * sc); o.w = f2bf(acc.w * sc);
    *(ushort4*)(aggb + (size_t)n * 256 + lane * 4) = o;
}

// ------------------------------------------------ bf16 MFMA GEMM (m97 structure)
// A: MxK bf16 row-major; Bt: NxK bf16 row-major (pre-transposed); C: MxN fp32
template <bool LEAKY>
__global__ __launch_bounds__(256) void gemm_mfma(
        const unsigned short* __restrict__ A, const unsigned short* __restrict__ Bt,
        const float* __restrict__ bias, float* __restrict__ C,
        int M, int N, int K) {
    __shared__ __align__(16) unsigned short As[128 * 32];
    __shared__ __align__(16) unsigned short Bs[128 * 32];
    const int tid = threadIdx.x;
    const int lane = tid & 63;
    const int w = tid >> 6;
    const int wr = (w >> 1) * 64;
    const int wc = (w & 1) * 64;
    const int rowBase = blockIdx.y * 128;
    const int colBase = blockIdx.x * 128;

    floatx4 acc[4][4];
#pragma unroll
    for (int i = 0; i < 4; i++)
#pragma unroll
        for (int j = 0; j < 4; j++) acc[i][j] = (floatx4){0.f, 0.f, 0.f, 0.f};

    const int srow = w * 32 + (lane >> 2);
    const int kc = (lane & 3) * 8;
    const unsigned short* gA = A + (size_t)(rowBase + srow) * K + kc;
    const unsigned short* gB = Bt + (size_t)(colBase + srow) * K + kc;
    unsigned short* lA = As + (w * 32) * 32;
    unsigned short* lB = Bs + (w * 32) * 32;

    const int q = lane >> 4;
    const int ln = lane & 15;

    for (int k0 = 0; k0 < K; k0 += 32) {
        __syncthreads();
        __builtin_amdgcn_global_load_lds((const GLOBAL_AS short*)(gA + k0),
                                         (LDS_AS short*)lA, 16, 0, 0);
        __builtin_amdgcn_global_load_lds((const GLOBAL_AS short*)(gA + k0 + (size_t)16 * K),
                                         (LDS_AS short*)(lA + 16 * 32), 16, 0, 0);
        __builtin_amdgcn_global_load_lds((const GLOBAL_AS short*)(gB + k0),
                                         (LDS_AS short*)lB, 16, 0, 0);
        __builtin_amdgcn_global_load_lds((const GLOBAL_AS short*)(gB + k0 + (size_t)16 * K),
                                         (LDS_AS short*)(lB + 16 * 32), 16, 0, 0);
        __syncthreads();
        short8 af[4], bf[4];
#pragma unroll
        for (int i = 0; i < 4; i++)
            af[i] = *(const short8*)(As + (wr + i * 16 + ln) * 32 + q * 8);
#pragma unroll
        for (int j = 0; j < 4; j++)
            bf[j] = *(const short8*)(Bs + (wc + j * 16 + ln) * 32 + q * 8);
#pragma unroll
        for (int i = 0; i < 4; i++)
#pragma unroll
            for (int j = 0; j < 4; j++)
                acc[i][j] = __builtin_amdgcn_mfma_f32_16x16x32_bf16(af[i], bf[j], acc[i][j], 0, 0, 0);
    }
#pragma unroll
    for (int i = 0; i < 4; i++) {
#pragma unroll
        for (int j = 0; j < 4; j++) {
#pragma unroll
            for (int r = 0; r < 4; r++) {
                int row = rowBase + wr + i * 16 + q * 4 + r;
                int col = colBase + wc + j * 16 + ln;
                float v = acc[i][j][r] + bias[col];
                if (LEAKY) v = v >= 0.f ? v : 0.01f * v;
                C[(size_t)row * N + col] = v;
            }
        }
    }
}

// ------------------------------------------------ LN over 256-wide row -> bf16 * ns[row]
// (fp32 writeback dropped: only the next aggregate consumes this)
__global__ __launch_bounds__(256) void k_ln256_scale(const float* __restrict__ h,
                                                     const float* __restrict__ ns,
                                                     unsigned short* __restrict__ hsb) {
    const float* p = h + (size_t)blockIdx.x * 256;
    float v = p[threadIdx.x];
    float s = v, s2 = v * v;
#pragma unroll
    for (int off = 32; off > 0; off >>= 1) {
        s += __shfl_down(s, off);
        s2 += __shfl_down(s2, off);
    }
    __shared__ float ss[4], ss2[4];
    int wave = threadIdx.x >> 6;
    if ((threadIdx.x & 63) == 0) { ss[wave] = s; ss2[wave] = s2; }
    __syncthreads();
    if (threadIdx.x == 0) {
        float t = 0.f, t2 = 0.f;
        for (int w = 0; w < 4; w++) { t += ss[w]; t2 += ss2[w]; }
        float mu = t / 256.f;
        float var = t2 / 256.f - mu * mu;
        ss[0] = mu;
        ss2[0] = rsqrtf(var + 1e-5f);
    }
    __syncthreads();
    float mu = ss[0], inv = ss2[0] * ns[blockIdx.x];
    hsb[(size_t)blockIdx.x * 256 + threadIdx.x] = f2bf((v - mu) * (ss2[0]) * ns[blockIdx.x] - mu * 0.f + (mu - mu));  // placeholder avoided below
}

// NOTE: the expression above must be (v - mu) * rstd * ns. Rewritten cleanly:
__global__ __launch_bounds__(256) void k_ln256_scale_v2(const float* __restrict__ h,
                                                        const float* __restrict__ ns,
                                                        unsigned short* __restrict__ hsb) {
    const float* p = h + (size_t)blockIdx.x * 256;
    float v = p[threadIdx.x];
    float s = v, s2 = v * v;
#pragma unroll
    for (int off = 32; off > 0; off >>= 1) {
        s += __shfl_down(s, off);
        s2 += __shfl_down(s2, off);
    }
    __shared__ float ss[4], ss2[4];
    int wave = threadIdx.x >> 6;
    if ((threadIdx.x & 63) == 0) { ss[wave] = s; ss2[wave] = s2; }
    __syncthreads();
    if (threadIdx.x == 0) {
        float t = 0.f, t2 = 0.f;
        for (int w = 0; w < 4; w++) { t += ss[w]; t2 += ss2[w]; }
        float mu = t / 256.f;
        float var = t2 / 256.f - mu * mu;
        ss[0] = mu;
        ss2[0] = rsqrtf(var + 1e-5f);
    }
    __syncthreads();
    float outv = (v - ss[0]) * ss2[0] * ns[blockIdx.x];
    hsb[(size_t)blockIdx.x * 256 + threadIdx.x] = f2bf(outv);
}

// ------------------------------------------------ fused per-node LN(1024) + partial mean-pool
// grid (8, 128): block handles 32 node rows of graph blockIdx.y; writes un-divided partial sum
__global__ __launch_bounds__(256) void k_lnpool(const float* __restrict__ h4,
                                                float* __restrict__ partial) {
    int g = blockIdx.y, p = blockIdx.x, t = threadIdx.x;
    int wave = t >> 6;
    __shared__ float ss[4], ss2[4];
    float4 acc = make_float4(0.f, 0.f, 0.f, 0.f);
    for (int i = 0; i < 32; i++) {
        int node = (g * 8 + p) * 32 + i;
        float4 v = *(const float4*)(h4 + (size_t)node * 1024 + t * 4);
        float s = v.x + v.y + v.z + v.w;
        float s2 = v.x * v.x + v.y * v.y + v.z * v.z + v.w * v.w;
#pragma unroll
        for (int off = 32; off > 0; off >>= 1) {
            s += __shfl_down(s, off);
            s2 += __shfl_down(s2, off);
        }
        if ((t & 63) == 0) { ss[wave] = s; ss2[wave] = s2; }
        __syncthreads();
        if (t == 0) {
            float tt = 0.f, tt2 = 0.f;
            for (int w = 0; w < 4; w++) { tt += ss[w]; tt2 += ss2[w]; }
            float mu = tt / 1024.f;
            float var = tt2 / 1024.f - mu * mu;
            ss[0] = mu;
            ss2[0] = rsqrtf(var + 1e-5f);
        }
        __syncthreads();
        float mu = ss[0], inv = ss2[0];
        acc.x += (v.x - mu) * inv;
        acc.y += (v.y - mu) * inv;
        acc.z += (v.z - mu) * inv;
        acc.w += (v.w - mu) * inv;
        __syncthreads();  // protect ss before next iter's writes
    }
    *(float4*)(partial + (size_t)(g * 8 + p) * 1024 + t * 4) = acc;
}

// ------------------------------------------------ final: sum 8 partials, /256, LN, -> bf16
__global__ __launch_bounds__(256) void k_pool_final(const float* __restrict__ partial,
                                                    unsigned short* __restrict__ pooledb) {
    int g = blockIdx.x, t = threadIdx.x;
    int wave = t >> 6;
    float4 a = make_float4(0.f, 0.f, 0.f, 0.f);
    for (int p = 0; p < 8; p++) {
        float4 v = *(const float4*)(partial + (size_t)(g * 8 + p) * 1024 + t * 4);
        a.x += v.x; a.y += v.y; a.z += v.z; a.w += v.w;
    }
    const float invn = 1.0f / 256.0f;
    a.x *= invn; a.y *= invn; a.z *= invn; a.w *= invn;
    float s = a.x + a.y + a.z + a.w;
    float s2 = a.x * a.x + a.y * a.y + a.z * a.z + a.w * a.w;
#pragma unroll
    for (int off = 32; off > 0; off >>= 1) {
        s += __shfl_down(s, off);
        s2 += __shfl_down(s2, off);
    }
    __shared__ float ss[4], ss2[4];
    if ((t & 63) == 0) { ss[wave] = s; ss2[wave] = s2; }
    __syncthreads();
    if (t == 0) {
        float tt = 0.f, tt2 = 0.f;
        for (int w = 0; w < 4; w++) { tt += ss[w]; tt2 += ss2[w]; }
        float mu = tt / 1024.f;
        float var = tt2 / 1024.f - mu * mu;
        ss[0] = mu;
        ss2[0] = rsqrtf(var + 1e-5f);
    }
    __syncthreads();
    float mu = ss[0], inv = ss2[0];
    ushort4 o;
    o.x = f2bf((a.x - mu) * inv); o.y = f2bf((a.y - mu) * inv);
    o.z = f2bf((a.z - mu) * inv); o.w = f2bf((a.w - mu) * inv);
    *(ushort4*)(pooledb + (size_t)g * 1024 + t * 4) = o;
}

// ---------------------------------------------------------------- launch
extern "C" void kernel_launch(void* const* d_in, const int* in_sizes, int n_in,
                              void* d_out, int out_size, void* d_ws, size_t ws_size,
                              hipStream_t stream) {
    const float* x  = (const float*)d_in[0];
    const int*   src = (const int*)d_in[1];
    const int*   dst = (const int*)d_in[2];
    const float* W1 = (const float*)d_in[3];  const float* b1 = (const float*)d_in[4];
    const float* W2 = (const float*)d_in[5];  const float* b2 = (const float*)d_in[6];
    const float* W3 = (const float*)d_in[7];  const float* b3 = (const float*)d_in[8];
    const float* W4 = (const float*)d_in[9];  const float* b4 = (const float*)d_in[10];
    const float* Wm = (const float*)d_in[11]; const float* bm = (const float*)d_in[12];
    const float* Wsd = (const float*)d_in[13]; const float* bsd = (const float*)d_in[14];
    float* out = (float*)d_out;

    char* w = (char*)d_ws;
    unsigned short* aggb = (unsigned short*)w; w += (size_t)N_NODES * 256 * 2;
    unsigned short* hsb  = (unsigned short*)w; w += (size_t)N_NODES * 256 * 2;  // scaled bf16 table
    float* h      = (float*)w; w += (size_t)N_NODES * 256 * 4;
    float* h4     = (float*)w; w += (size_t)N_NODES * 1024 * 4;
    float* partial = (float*)w; w += (size_t)128 * 8 * 1024 * 4;
    unsigned short* pooledb = (unsigned short*)w; w += (size_t)128 * 1024 * 2;
    unsigned short* W1t = (unsigned short*)w; w += (size_t)256 * 256 * 2;
    unsigned short* W2t = (unsigned short*)w; w += (size_t)256 * 256 * 2;
    unsigned short* W3t = (unsigned short*)w; w += (size_t)256 * 256 * 2;
    unsigned short* W4t = (unsigned short*)w; w += (size_t)256 * 1024 * 2;
    unsigned short* Wmt = (unsigned short*)w; w += (size_t)1024 * 1024 * 2;
    unsigned short* Wst = (unsigned short*)w; w += (size_t)1024 * 1024 * 2;
    float* ns     = (float*)w; w += (size_t)N_NODES * 4;
    float* nd     = (float*)w; w += (size_t)N_NODES * 4;
    int* out_deg  = (int*)w;   w += (size_t)N_NODES * 4;
    int* in_deg   = (int*)w;   w += (size_t)N_NODES * 4;
    int* row_ptr  = (int*)w;   w += (size_t)(N_NODES + 1) * 4;
    int* cursor   = (int*)w;   w += (size_t)N_NODES * 4;
    int* csr_src  = (int*)w;   w += (size_t)N_EDGES * 4;

    // weights -> bf16, transposed to [N][K]
    k_transpose_bf16<<<dim3(256 / 32, 256 / 32), 256, 0, stream>>>(W1, W1t, 256, 256);
    k_transpose_bf16<<<dim3(256 / 32, 256 / 32), 256, 0, stream>>>(W2, W2t, 256, 256);
    k_transpose_bf16<<<dim3(256 / 32, 256 / 32), 256, 0, stream>>>(W3, W3t, 256, 256);
    k_transpose_bf16<<<dim3(1024 / 32, 256 / 32), 256, 0, stream>>>(W4, W4t, 256, 1024);
    k_transpose_bf16<<<dim3(1024 / 32, 1024 / 32), 256, 0, stream>>>(Wm, Wmt, 1024, 1024);
    k_transpose_bf16<<<dim3(1024 / 32, 1024 / 32), 256, 0, stream>>>(Wsd, Wst, 1024, 1024);

    // graph preprocessing
    k_zero_ints<<<(2 * N_NODES + 255) / 256, 256, 0, stream>>>(out_deg, 2 * N_NODES);
    k_count_deg<<<N_EDGES / 256, 256, 0, stream>>>(src, dst, out_deg, in_deg);
    k_norms<<<N_NODES / 256, 256, 0, stream>>>(out_deg, in_deg, ns, nd);
    k_scan<<<1, 1024, 0, stream>>>(in_deg, row_ptr, cursor);
    k_build_csr<<<N_EDGES / 256, 256, 0, stream>>>(src, dst, cursor, csr_src);

    // layer-1 gather table: x * ns -> bf16
    k_scale_x<<<N_NODES * 256 / 1024, 256, 0, stream>>>(x, ns, hsb);

    // layer 1
    k_aggregate<<<N_NODES / 4, 256, 0, stream>>>(hsb, row_ptr, csr_src, nd, aggb);
    gemm_mfma<true><<<dim3(2, N_NODES / 128), 256, 0, stream>>>(aggb, W1t, b1, h, N_NODES, 256, 256);
    k_ln256_scale_v2<<<N_NODES, 256, 0, stream>>>(h, ns, hsb);

    // layer 2
    k_aggregate<<<N_NODES / 4, 256, 0, stream>>>(hsb, row_ptr, csr_src, nd, aggb);
    gemm_mfma<true><<<dim3(2, N_NODES / 128), 256, 0, stream>>>(aggb, W2t, b2, h, N_NODES, 256, 256);
    k_ln256_scale_v2<<<N_NODES, 256, 0, stream>>>(h, ns, hsb);

    // layer 3
    k_aggregate<<<N_NODES / 4, 256, 0, stream>>>(hsb, row_ptr, csr_src, nd, aggb);
    gemm_mfma<true><<<dim3(2, N_NODES / 128), 256, 0, stream>>>(aggb, W3t, b3, h, N_NODES, 256, 256);
    k_ln256_scale_v2<<<N_NODES, 256, 0, stream>>>(h, ns, hsb);

    // layer 4 (256 -> 1024); LN fused into pool
    k_aggregate<<<N_NODES / 4, 256, 0, stream>>>(hsb, row_ptr, csr_src, nd, aggb);
    gemm_mfma<true><<<dim3(1024 / 128, N_NODES / 128), 256, 0, stream>>>(aggb, W4t, b4, h4, N_NODES, 1024, 256);

    // per-node LN + mean pool + final LN -> bf16
    k_lnpool<<<dim3(8, 128), 256, 0, stream>>>(h4, partial);
    k_pool_final<<<128, 256, 0, stream>>>(partial, pooledb);

    // heads
    gemm_mfma<false><<<dim3(1024 / 128, 1), 256, 0, stream>>>(pooledb, Wmt, bm, out, 128, 1024, 1024);
    gemm_mfma<false><<<dim3(1024 / 128, 1), 256, 0, stream>>>(pooledb, Wst, bsd, out + 128 * 1024, 128, 1024, 1024);
}

// Round 4
// 551.396 us; speedup vs baseline: 2.7561x; 1.0729x over previous
//
#include <hip/hip_runtime.h>

#define N_NODES 32768
#define N_EDGES 524288

typedef __attribute__((ext_vector_type(8))) short short8;
typedef __attribute__((ext_vector_type(4))) float floatx4;

#define GLOBAL_AS __attribute__((address_space(1)))
#define LDS_AS __attribute__((address_space(3)))

__device__ __forceinline__ unsigned short f2bf(float x) {
    union { float f; unsigned u; } v; v.f = x;
    unsigned r = v.u + 0x7FFF + ((v.u >> 16) & 1);
    return (unsigned short)(r >> 16);
}
__device__ __forceinline__ float bf2f(unsigned short u) {
    union { unsigned u; float f; } v; v.u = ((unsigned)u) << 16;
    return v.f;
}

// ---------------------------------------------------------------- utility
__global__ void k_zero_ints(int* __restrict__ p, int n) {
    int i = blockIdx.x * 256 + threadIdx.x;
    if (i < n) p[i] = 0;
}

__global__ void k_count_deg(const int* __restrict__ src, const int* __restrict__ dst,
                            int* __restrict__ out_deg, int* __restrict__ in_deg) {
    int e = blockIdx.x * 256 + threadIdx.x;
    if (e < N_EDGES) {
        atomicAdd(&out_deg[src[e]], 1);
        atomicAdd(&in_deg[dst[e]], 1);
    }
}

__global__ void k_norms(const int* __restrict__ out_deg, const int* __restrict__ in_deg,
                        float* __restrict__ ns, float* __restrict__ nd) {
    int i = blockIdx.x * 256 + threadIdx.x;
    if (i < N_NODES) {
        int od = out_deg[i], id = in_deg[i];
        ns[i] = od > 0 ? rsqrtf((float)od) : 1.0f;
        nd[i] = id > 0 ? rsqrtf((float)id) : 1.0f;
    }
}

__global__ void k_scan(const int* __restrict__ in_deg, int* __restrict__ row_ptr,
                       int* __restrict__ cursor) {
    __shared__ int part[1024];
    int t = threadIdx.x;
    int base = t * 32;
    int local[32];
    int s = 0;
    for (int i = 0; i < 32; i++) { local[i] = s; s += in_deg[base + i]; }
    part[t] = s;
    __syncthreads();
    for (int off = 1; off < 1024; off <<= 1) {
        int v = (t >= off) ? part[t - off] : 0;
        __syncthreads();
        part[t] += v;
        __syncthreads();
    }
    int prev = (t == 0) ? 0 : part[t - 1];
    for (int i = 0; i < 32; i++) {
        int v = prev + local[i];
        row_ptr[base + i] = v;
        cursor[base + i] = v;
    }
    if (t == 1023) row_ptr[N_NODES] = part[1023];
}

__global__ void k_build_csr(const int* __restrict__ src, const int* __restrict__ dst,
                            int* __restrict__ cursor, int* __restrict__ csr_src) {
    int e = blockIdx.x * 256 + threadIdx.x;
    if (e < N_EDGES) {
        int p = atomicAdd(&cursor[dst[e]], 1);
        csr_src[p] = src[e];
    }
}

// ---------------------------------------------- weight transpose fp32[K][N] -> bf16[N][K]
__global__ __launch_bounds__(256) void k_transpose_bf16(const float* __restrict__ W,
                                                        unsigned short* __restrict__ Wt,
                                                        int K, int N) {
    __shared__ float t[32][33];
    int tx = threadIdx.x & 31, ty = threadIdx.x >> 5;  // ty 0..7
    int n0 = blockIdx.x * 32, k0 = blockIdx.y * 32;
    for (int r = 0; r < 32; r += 8)
        t[ty + r][tx] = W[(size_t)(k0 + ty + r) * N + n0 + tx];
    __syncthreads();
    for (int r = 0; r < 32; r += 8) {
        int n = ty + r;
        Wt[(size_t)(n0 + n) * K + k0 + tx] = f2bf(t[tx][n]);
    }
}

// ---------------------------------------------- x * ns[node] -> bf16 table (layer-1 gather input)
__global__ __launch_bounds__(256) void k_scale_x(const float* __restrict__ x,
                                                 const float* __restrict__ ns,
                                                 unsigned short* __restrict__ xsb) {
    int i = blockIdx.x * 256 + threadIdx.x;  // float4 index
    float4 v = ((const float4*)x)[i];
    float sc = ns[i >> 6];  // 64 float4 per 256-wide row
    ushort4 o;
    o.x = f2bf(v.x * sc); o.y = f2bf(v.y * sc);
    o.z = f2bf(v.z * sc); o.w = f2bf(v.w * sc);
    ((ushort4*)xsb)[i] = o;
}

// ------------------------------------------------ aggregation (gather, CSR by dst)
// table hs is bf16, pre-scaled by ns[src]. TWO nodes per wave: half = lane>>5 picks
// the node, hl = lane&31 owns 8 features (16B). One load instr = two 512B rows.
__global__ __launch_bounds__(256) void k_aggregate(
        const unsigned short* __restrict__ hs, const int* __restrict__ row_ptr,
        const int* __restrict__ csr_src, const float* __restrict__ nd,
        unsigned short* __restrict__ aggb) {
    int wave = threadIdx.x >> 6, lane = threadIdx.x & 63;
    int half = lane >> 5, hl = lane & 31;
    int n = (blockIdx.x * 4 + wave) * 2 + half;
    int beg = row_ptr[n], end = row_ptr[n + 1];
    float acc[8];
#pragma unroll
    for (int k = 0; k < 8; k++) acc[k] = 0.f;
    const unsigned short* hp = hs + hl * 8;
    int e = beg;
    for (; e + 4 <= end; e += 4) {
        int s0 = csr_src[e], s1 = csr_src[e + 1], s2 = csr_src[e + 2], s3 = csr_src[e + 3];
        short8 v0 = *(const short8*)(hp + (size_t)s0 * 256);
        short8 v1 = *(const short8*)(hp + (size_t)s1 * 256);
        short8 v2 = *(const short8*)(hp + (size_t)s2 * 256);
        short8 v3 = *(const short8*)(hp + (size_t)s3 * 256);
#pragma unroll
        for (int k = 0; k < 8; k++)
            acc[k] += (bf2f((unsigned short)v0[k]) + bf2f((unsigned short)v1[k])) +
                      (bf2f((unsigned short)v2[k]) + bf2f((unsigned short)v3[k]));
    }
    for (; e < end; e++) {
        int s = csr_src[e];
        short8 v = *(const short8*)(hp + (size_t)s * 256);
#pragma unroll
        for (int k = 0; k < 8; k++) acc[k] += bf2f((unsigned short)v[k]);
    }
    float sc = nd[n];
    short8 o;
#pragma unroll
    for (int k = 0; k < 8; k++) o[k] = (short)f2bf(acc[k] * sc);
    *(short8*)(aggb + (size_t)n * 256 + hl * 8) = o;
}

// ------------------------------------------------ bf16 MFMA GEMM (m97 structure)
// A: MxK bf16 row-major; Bt: NxK bf16 row-major; C: MxN (fp32 or bf16).
// SPLIT: N=2*NH, cols [0,NH) -> C with bias, cols [NH,2NH) -> C2 with bias2.
template <bool LEAKY, bool OUT_BF16, bool SPLIT>
__global__ __launch_bounds__(256) void gemm_mfma(
        const unsigned short* __restrict__ A, const unsigned short* __restrict__ Bt,
        const float* __restrict__ bias, const float* __restrict__ bias2,
        void* __restrict__ Cv, void* __restrict__ C2v,
        int M, int N, int K) {
    __shared__ __align__(16) unsigned short As[128 * 32];
    __shared__ __align__(16) unsigned short Bs[128 * 32];
    const int tid = threadIdx.x;
    const int lane = tid & 63;
    const int w = tid >> 6;
    const int wr = (w >> 1) * 64;
    const int wc = (w & 1) * 64;
    const int rowBase = blockIdx.y * 128;
    const int colBase = blockIdx.x * 128;

    floatx4 acc[4][4];
#pragma unroll
    for (int i = 0; i < 4; i++)
#pragma unroll
        for (int j = 0; j < 4; j++) acc[i][j] = (floatx4){0.f, 0.f, 0.f, 0.f};

    const int srow = w * 32 + (lane >> 2);
    const int kc = (lane & 3) * 8;
    const unsigned short* gA = A + (size_t)(rowBase + srow) * K + kc;
    const unsigned short* gB = Bt + (size_t)(colBase + srow) * K + kc;
    unsigned short* lA = As + (w * 32) * 32;
    unsigned short* lB = Bs + (w * 32) * 32;

    const int q = lane >> 4;
    const int ln = lane & 15;

    for (int k0 = 0; k0 < K; k0 += 32) {
        __syncthreads();
        __builtin_amdgcn_global_load_lds((const GLOBAL_AS short*)(gA + k0),
                                         (LDS_AS short*)lA, 16, 0, 0);
        __builtin_amdgcn_global_load_lds((const GLOBAL_AS short*)(gA + k0 + (size_t)16 * K),
                                         (LDS_AS short*)(lA + 16 * 32), 16, 0, 0);
        __builtin_amdgcn_global_load_lds((const GLOBAL_AS short*)(gB + k0),
                                         (LDS_AS short*)lB, 16, 0, 0);
        __builtin_amdgcn_global_load_lds((const GLOBAL_AS short*)(gB + k0 + (size_t)16 * K),
                                         (LDS_AS short*)(lB + 16 * 32), 16, 0, 0);
        __syncthreads();
        short8 af[4], bf[4];
#pragma unroll
        for (int i = 0; i < 4; i++)
            af[i] = *(const short8*)(As + (wr + i * 16 + ln) * 32 + q * 8);
#pragma unroll
        for (int j = 0; j < 4; j++)
            bf[j] = *(const short8*)(Bs + (wc + j * 16 + ln) * 32 + q * 8);
#pragma unroll
        for (int i = 0; i < 4; i++)
#pragma unroll
            for (int j = 0; j < 4; j++)
                acc[i][j] = __builtin_amdgcn_mfma_f32_16x16x32_bf16(af[i], bf[j], acc[i][j], 0, 0, 0);
    }
    const int NH = N >> 1;  // SPLIT halves (block-uniform selection: NH % 128 == 0)
#pragma unroll
    for (int i = 0; i < 4; i++) {
#pragma unroll
        for (int j = 0; j < 4; j++) {
#pragma unroll
            for (int r = 0; r < 4; r++) {
                int row = rowBase + wr + i * 16 + q * 4 + r;
                int col = colBase + wc + j * 16 + ln;
                float b, *Cf; unsigned short* Cb; int cw, ccol;
                if (SPLIT) {
                    bool hi = col >= NH;
                    b = hi ? bias2[col - NH] : bias[col];
                    Cf = (float*)(hi ? C2v : Cv);
                    cw = NH; ccol = hi ? col - NH : col;
                } else {
                    b = bias[col];
                    Cf = (float*)Cv; Cb = (unsigned short*)Cv;
                    cw = N; ccol = col;
                }
                float v = acc[i][j][r] + b;
                if (LEAKY) v = v >= 0.f ? v : 0.01f * v;
                if (OUT_BF16)
                    ((unsigned short*)Cv)[(size_t)row * cw + ccol] = f2bf(v);
                else
                    Cf[(size_t)row * cw + ccol] = v;
            }
        }
    }
}

// ------------------------------------------------ LN over 256-wide bf16 row -> bf16 * ns[row]
__global__ __launch_bounds__(256) void k_ln256_scale(const unsigned short* __restrict__ h,
                                                     const float* __restrict__ ns,
                                                     unsigned short* __restrict__ hsb) {
    float v = bf2f(h[(size_t)blockIdx.x * 256 + threadIdx.x]);
    float s = v, s2 = v * v;
#pragma unroll
    for (int off = 32; off > 0; off >>= 1) {
        s += __shfl_down(s, off);
        s2 += __shfl_down(s2, off);
    }
    __shared__ float ss[4], ss2[4];
    int wave = threadIdx.x >> 6;
    if ((threadIdx.x & 63) == 0) { ss[wave] = s; ss2[wave] = s2; }
    __syncthreads();
    if (threadIdx.x == 0) {
        float t = 0.f, t2 = 0.f;
        for (int w = 0; w < 4; w++) { t += ss[w]; t2 += ss2[w]; }
        float mu = t / 256.f;
        float var = t2 / 256.f - mu * mu;
        ss[0] = mu;
        ss2[0] = rsqrtf(var + 1e-5f);
    }
    __syncthreads();
    float outv = (v - ss[0]) * ss2[0] * ns[blockIdx.x];
    hsb[(size_t)blockIdx.x * 256 + threadIdx.x] = f2bf(outv);
}

// ------------------------------------------------ fused per-node LN(1024) + partial mean-pool
// grid (8, 128): block handles 32 bf16 node rows of graph blockIdx.y
__global__ __launch_bounds__(256) void k_lnpool(const unsigned short* __restrict__ h4,
                                                float* __restrict__ partial) {
    int g = blockIdx.y, p = blockIdx.x, t = threadIdx.x;
    int wave = t >> 6;
    __shared__ float ss[4], ss2[4];
    float4 acc = make_float4(0.f, 0.f, 0.f, 0.f);
    for (int i = 0; i < 32; i++) {
        int node = (g * 8 + p) * 32 + i;
        ushort4 vb = *(const ushort4*)(h4 + (size_t)node * 1024 + t * 4);
        float4 v = make_float4(bf2f(vb.x), bf2f(vb.y), bf2f(vb.z), bf2f(vb.w));
        float s = v.x + v.y + v.z + v.w;
        float s2 = v.x * v.x + v.y * v.y + v.z * v.z + v.w * v.w;
#pragma unroll
        for (int off = 32; off > 0; off >>= 1) {
            s += __shfl_down(s, off);
            s2 += __shfl_down(s2, off);
        }
        if ((t & 63) == 0) { ss[wave] = s; ss2[wave] = s2; }
        __syncthreads();
        if (t == 0) {
            float tt = 0.f, tt2 = 0.f;
            for (int w = 0; w < 4; w++) { tt += ss[w]; tt2 += ss2[w]; }
            float mu = tt / 1024.f;
            float var = tt2 / 1024.f - mu * mu;
            ss[0] = mu;
            ss2[0] = rsqrtf(var + 1e-5f);
        }
        __syncthreads();
        float mu = ss[0], inv = ss2[0];
        acc.x += (v.x - mu) * inv;
        acc.y += (v.y - mu) * inv;
        acc.z += (v.z - mu) * inv;
        acc.w += (v.w - mu) * inv;
        __syncthreads();
    }
    *(float4*)(partial + (size_t)(g * 8 + p) * 1024 + t * 4) = acc;
}

// ------------------------------------------------ final: sum 8 partials, /256, LN, -> bf16
__global__ __launch_bounds__(256) void k_pool_final(const float* __restrict__ partial,
                                                    unsigned short* __restrict__ pooledb) {
    int g = blockIdx.x, t = threadIdx.x;
    int wave = t >> 6;
    float4 a = make_float4(0.f, 0.f, 0.f, 0.f);
    for (int p = 0; p < 8; p++) {
        float4 v = *(const float4*)(partial + (size_t)(g * 8 + p) * 1024 + t * 4);
        a.x += v.x; a.y += v.y; a.z += v.z; a.w += v.w;
    }
    const float invn = 1.0f / 256.0f;
    a.x *= invn; a.y *= invn; a.z *= invn; a.w *= invn;
    float s = a.x + a.y + a.z + a.w;
    float s2 = a.x * a.x + a.y * a.y + a.z * a.z + a.w * a.w;
#pragma unroll
    for (int off = 32; off > 0; off >>= 1) {
        s += __shfl_down(s, off);
        s2 += __shfl_down(s2, off);
    }
    __shared__ float ss[4], ss2[4];
    if ((t & 63) == 0) { ss[wave] = s; ss2[wave] = s2; }
    __syncthreads();
    if (t == 0) {
        float tt = 0.f, tt2 = 0.f;
        for (int w = 0; w < 4; w++) { tt += ss[w]; tt2 += ss2[w]; }
        float mu = tt / 1024.f;
        float var = tt2 / 1024.f - mu * mu;
        ss[0] = mu;
        ss2[0] = rsqrtf(var + 1e-5f);
    }
    __syncthreads();
    float mu = ss[0], inv = ss2[0];
    ushort4 o;
    o.x = f2bf((a.x - mu) * inv); o.y = f2bf((a.y - mu) * inv);
    o.z = f2bf((a.z - mu) * inv); o.w = f2bf((a.w - mu) * inv);
    *(ushort4*)(pooledb + (size_t)g * 1024 + t * 4) = o;
}

// ---------------------------------------------------------------- launch
extern "C" void kernel_launch(void* const* d_in, const int* in_sizes, int n_in,
                              void* d_out, int out_size, void* d_ws, size_t ws_size,
                              hipStream_t stream) {
    const float* x  = (const float*)d_in[0];
    const int*   src = (const int*)d_in[1];
    const int*   dst = (const int*)d_in[2];
    const float* W1 = (const float*)d_in[3];  const float* b1 = (const float*)d_in[4];
    const float* W2 = (const float*)d_in[5];  const float* b2 = (const float*)d_in[6];
    const float* W3 = (const float*)d_in[7];  const float* b3 = (const float*)d_in[8];
    const float* W4 = (const float*)d_in[9];  const float* b4 = (const float*)d_in[10];
    const float* Wm = (const float*)d_in[11]; const float* bm = (const float*)d_in[12];
    const float* Wsd = (const float*)d_in[13]; const float* bsd = (const float*)d_in[14];
    float* out = (float*)d_out;

    char* w = (char*)d_ws;
    unsigned short* aggb = (unsigned short*)w; w += (size_t)N_NODES * 256 * 2;
    unsigned short* hsb  = (unsigned short*)w; w += (size_t)N_NODES * 256 * 2;  // LN*ns bf16 table
    unsigned short* hb   = (unsigned short*)w; w += (size_t)N_NODES * 256 * 2;  // GEMM out bf16
    unsigned short* h4b  = (unsigned short*)w; w += (size_t)N_NODES * 1024 * 2;
    float* partial = (float*)w; w += (size_t)128 * 8 * 1024 * 4;
    unsigned short* pooledb = (unsigned short*)w; w += (size_t)128 * 1024 * 2;
    unsigned short* W1t = (unsigned short*)w; w += (size_t)256 * 256 * 2;
    unsigned short* W2t = (unsigned short*)w; w += (size_t)256 * 256 * 2;
    unsigned short* W3t = (unsigned short*)w; w += (size_t)256 * 256 * 2;
    unsigned short* W4t = (unsigned short*)w; w += (size_t)256 * 1024 * 2;
    unsigned short* Wmt = (unsigned short*)w; w += (size_t)1024 * 1024 * 2;  // Wst must follow
    unsigned short* Wst = (unsigned short*)w; w += (size_t)1024 * 1024 * 2;  // contiguous: cat
    float* ns     = (float*)w; w += (size_t)N_NODES * 4;
    float* nd     = (float*)w; w += (size_t)N_NODES * 4;
    int* out_deg  = (int*)w;   w += (size_t)N_NODES * 4;
    int* in_deg   = (int*)w;   w += (size_t)N_NODES * 4;
    int* row_ptr  = (int*)w;   w += (size_t)(N_NODES + 1) * 4;
    int* cursor   = (int*)w;   w += (size_t)N_NODES * 4;
    int* csr_src  = (int*)w;   w += (size_t)N_EDGES * 4;

    // weights -> bf16, transposed to [N][K]
    k_transpose_bf16<<<dim3(8, 8), 256, 0, stream>>>(W1, W1t, 256, 256);
    k_transpose_bf16<<<dim3(8, 8), 256, 0, stream>>>(W2, W2t, 256, 256);
    k_transpose_bf16<<<dim3(8, 8), 256, 0, stream>>>(W3, W3t, 256, 256);
    k_transpose_bf16<<<dim3(32, 8), 256, 0, stream>>>(W4, W4t, 256, 1024);
    k_transpose_bf16<<<dim3(32, 32), 256, 0, stream>>>(Wm, Wmt, 1024, 1024);
    k_transpose_bf16<<<dim3(32, 32), 256, 0, stream>>>(Wsd, Wst, 1024, 1024);

    // graph preprocessing
    k_zero_ints<<<(2 * N_NODES + 255) / 256, 256, 0, stream>>>(out_deg, 2 * N_NODES);
    k_count_deg<<<N_EDGES / 256, 256, 0, stream>>>(src, dst, out_deg, in_deg);
    k_norms<<<N_NODES / 256, 256, 0, stream>>>(out_deg, in_deg, ns, nd);
    k_scan<<<1, 1024, 0, stream>>>(in_deg, row_ptr, cursor);
    k_build_csr<<<N_EDGES / 256, 256, 0, stream>>>(src, dst, cursor, csr_src);

    // layer-1 gather table: x * ns -> bf16
    k_scale_x<<<N_NODES * 256 / 1024, 256, 0, stream>>>(x, ns, hsb);

    // layers 1-3: aggregate -> GEMM(bf16 out, leaky) -> LN*ns -> bf16 table
    const unsigned short* Wts[3] = {W1t, W2t, W3t};
    const float* bs3[3] = {b1, b2, b3};
    for (int l = 0; l < 3; l++) {
        k_aggregate<<<N_NODES / 8, 256, 0, stream>>>(hsb, row_ptr, csr_src, nd, aggb);
        gemm_mfma<true, true, false><<<dim3(2, N_NODES / 128), 256, 0, stream>>>(
            aggb, Wts[l], bs3[l], nullptr, hb, nullptr, N_NODES, 256, 256);
        k_ln256_scale<<<N_NODES, 256, 0, stream>>>(hb, ns, hsb);
    }

    // layer 4 (256 -> 1024), bf16 out; LN fused into pool
    k_aggregate<<<N_NODES / 8, 256, 0, stream>>>(hsb, row_ptr, csr_src, nd, aggb);
    gemm_mfma<true, true, false><<<dim3(8, N_NODES / 128), 256, 0, stream>>>(
        aggb, W4t, b4, nullptr, h4b, nullptr, N_NODES, 1024, 256);

    // per-node LN + mean pool + final LN -> bf16
    k_lnpool<<<dim3(8, 128), 256, 0, stream>>>(h4b, partial);
    k_pool_final<<<128, 256, 0, stream>>>(partial, pooledb);

    // both heads in one GEMM: Bt = [Wmt ; Wst] (contiguous), N=2048, split outputs
    gemm_mfma<false, false, true><<<dim3(16, 1), 256, 0, stream>>>(
        pooledb, Wmt, bm, bsd, out, out + 128 * 1024, 128, 2048, 1024);
}